// Round 3
// baseline (221.628 us; speedup 1.0000x reference)
//
#include <hip/hip_runtime.h>

#define HW    3136      // 56*56
#define WIDTH 56
#define C     256
#define CR    64
#define NT    64
#define TT    8

#define BN_INV 0.9999950000374997f   // 1/sqrt(1+1e-5)

typedef __attribute__((ext_vector_type(8))) short short8;
typedef __attribute__((ext_vector_type(4))) float f32x4;

static __device__ __forceinline__ float relu(float v) { return fmaxf(v, 0.0f); }

static __device__ __forceinline__ unsigned short f2bf(float f) {
    unsigned u = __builtin_bit_cast(unsigned, f);
    unsigned r = (u + 0x7FFFu + ((u >> 16) & 1u)) >> 16;   // RNE
    return (unsigned short)r;
}

// k0: convert conv21_w [CR][C] fp32 -> bf16 (k-contiguous for MFMA A)
__global__ __launch_bounds__(256) void k0_cvt_w(const float* __restrict__ w,
                                                unsigned short* __restrict__ wbf) {
    int i = blockIdx.x * 256 + threadIdx.x;   // 0..16383
    wbf[i] = f2bf(w[i]);
}

// k1: y[nt,o,p] = relu(bn21( sum_c w[o,c] * x[nt,c,p] ))  via MFMA bf16.
// Barrier-free K-loop: wave wv owns frame nt = 4*(blk/49)+wv, pixel strip
// (blk%49)*64, all 64 outputs. Private LDS B-tile per wave; A staged once.
__global__ __launch_bounds__(256, 2) void k1_mfma(const float* __restrict__ x,
                                                  const unsigned short* __restrict__ wbf,
                                                  const float* __restrict__ g,
                                                  const float* __restrict__ bb,
                                                  float* __restrict__ y) {
    __shared__ unsigned short Alds[64][264];     // 64 o x (256 c + 8 pad) = 33 KB
    __shared__ unsigned short Blds[4][64][40];   // per-wave: 64 pix x (32 c + 8 pad) = 20 KB

    const int tid  = threadIdx.x;
    const int lane = tid & 63;
    const int wv   = tid >> 6;
    const int blk  = blockIdx.x;
    const int gq   = blk / 49;                 // 0..15
    const int s    = blk - gq * 49;            // 0..48
    const int p0   = s * 64;
    const int nt   = __builtin_amdgcn_readfirstlane(gq * 4 + wv);

    // stage A once (all 256 threads)
    {
        const int o  = tid >> 2;
        const int cb = (tid & 3) * 64;
        const unsigned short* wp = wbf + o * C + cb;
        unsigned short* ap = &Alds[o][cb];
#pragma unroll
        for (int j = 0; j < 8; ++j)
            *(short8*)(ap + j * 8) = *(const short8*)(wp + j * 8);
    }
    __syncthreads();   // the only barrier

    const float* xw = x + (size_t)nt * (C * HW) + p0 + lane;
    unsigned short (*Bw)[40] = Blds[wv];

    f32x4 acc[4][4];   // [nb(pixel block)][mb(output block)]
#pragma unroll
    for (int nb = 0; nb < 4; ++nb)
#pragma unroll
        for (int mb = 0; mb < 4; ++mb) acc[nb][mb] = (f32x4)0.0f;

    const int frow = lane & 15;
    const int fk8  = (lane >> 4) * 8;

    float buf[2][32];
#pragma unroll
    for (int j = 0; j < 32; ++j) buf[0][j] = xw[(size_t)j * HW];

#pragma unroll
    for (int ks = 0; ks < 8; ++ks) {
        const int cur = ks & 1;
        // issue next K-step's 32 loads (register double-buffer, no barrier)
        if (ks < 7) {
            const float* xn = xw + (size_t)((ks + 1) * 32) * HW;
#pragma unroll
            for (int j = 0; j < 32; ++j) buf[cur ^ 1][j] = xn[(size_t)j * HW];
        }
        // convert current 32 channels -> own LDS row (wave-private, in-order DS)
#pragma unroll
        for (int q = 0; q < 4; ++q) {
            union { unsigned short u[8]; short8 v; } pk;
#pragma unroll
            for (int j = 0; j < 8; ++j) pk.u[j] = f2bf(buf[cur][q * 8 + j]);
            *(short8*)&Bw[lane][q * 8] = pk.v;
        }
        // fragments + 16 MFMA
        short8 bfrag[4], afrag[4];
#pragma unroll
        for (int nb = 0; nb < 4; ++nb)
            bfrag[nb] = *(const short8*)&Bw[nb * 16 + frow][fk8];
#pragma unroll
        for (int mb = 0; mb < 4; ++mb)
            afrag[mb] = *(const short8*)&Alds[mb * 16 + frow][ks * 32 + fk8];
#pragma unroll
        for (int nb = 0; nb < 4; ++nb)
#pragma unroll
            for (int mb = 0; mb < 4; ++mb)
                acc[nb][mb] = __builtin_amdgcn_mfma_f32_16x16x32_bf16(
                    afrag[mb], bfrag[nb], acc[nb][mb], 0, 0, 0);
    }

    // epilogue: D col = lane&15 (pixel), row = (lane>>4)*4 + r (output o)
    float* yp = y + (size_t)nt * (CR * HW);
    const int rbase = (lane >> 4) * 4;
#pragma unroll
    for (int nb = 0; nb < 4; ++nb) {
        const int p = p0 + nb * 16 + frow;
#pragma unroll
        for (int mb = 0; mb < 4; ++mb)
#pragma unroll
            for (int r = 0; r < 4; ++r) {
                int o = mb * 16 + rbase + r;
                float v = fmaf(acc[nb][mb][r], g[o] * BN_INV, bb[o]);
                yp[(size_t)o * HW + p] = relu(v);
            }
    }
}

// k2: cv[nt,k,p] = relu(bn22( (1/CR) * sum_ch y[nt,ch,p] * y[nt2,ch,p+off(k)] ))
// float4: thread = (nt, row, col4). 64-thr blocks, grid 784.
__global__ __launch_bounds__(64) void k2_corr(const float* __restrict__ y,
                                              const float* __restrict__ g,
                                              const float* __restrict__ bb,
                                              float* __restrict__ cv) {
    int gt = blockIdx.x * 64 + threadIdx.x;    // 0..50175
    int nt = gt / 784;
    int rm = gt - nt * 784;
    int r  = rm / 14;
    int c4 = rm - r * 14;
    int p  = r * WIDTH + c4 * 4;

    int t   = nt & (TT - 1);
    int nt2 = (t < TT - 1) ? nt + 1 : nt;

    const float* y1 = y + (size_t)nt  * (CR * HW) + p;
    const float* y2 = y + (size_t)nt2 * (CR * HW) + p;

    const bool lv = (c4 > 0), rv = (c4 < 13);
    const bool rowv0 = (r > 0), rowv2 = (r < WIDTH - 1);

    f32x4 acc[9];
#pragma unroll
    for (int k = 0; k < 9; ++k) acc[k] = (f32x4)0.0f;

#pragma unroll 2
    for (int ch = 0; ch < CR; ++ch) {
        f32x4 a = *(const f32x4*)(y1 + (size_t)ch * HW);
        const float* b = y2 + (size_t)ch * HW;
#pragma unroll
        for (int dy = 0; dy < 3; ++dy) {
            bool okr = (dy == 0) ? rowv0 : ((dy == 2) ? rowv2 : true);
            const float* row = b + (dy - 1) * WIDTH;
            f32x4 Cm = *(const f32x4*)row;        // cols p..p+3 (16B aligned)
            float lval = row[-1];
            float rval = row[4];
            // select (not multiply) so garbage never propagates; a is always finite
            f32x4 Cv;
            Cv.x = okr ? Cm.x : 0.0f;  Cv.y = okr ? Cm.y : 0.0f;
            Cv.z = okr ? Cm.z : 0.0f;  Cv.w = okr ? Cm.w : 0.0f;
            float lq = (okr && lv) ? lval : 0.0f;
            float rq = (okr && rv) ? rval : 0.0f;
            int k0i = dy * 3;
            // dx = -1 : window (l, C.x, C.y, C.z)
            acc[k0i].x = fmaf(a.x, lq,   acc[k0i].x);
            acc[k0i].y = fmaf(a.y, Cv.x, acc[k0i].y);
            acc[k0i].z = fmaf(a.z, Cv.y, acc[k0i].z);
            acc[k0i].w = fmaf(a.w, Cv.z, acc[k0i].w);
            // dx = 0 : window C
            acc[k0i+1].x = fmaf(a.x, Cv.x, acc[k0i+1].x);
            acc[k0i+1].y = fmaf(a.y, Cv.y, acc[k0i+1].y);
            acc[k0i+1].z = fmaf(a.z, Cv.z, acc[k0i+1].z);
            acc[k0i+1].w = fmaf(a.w, Cv.w, acc[k0i+1].w);
            // dx = +1 : window (C.y, C.z, C.w, r)
            acc[k0i+2].x = fmaf(a.x, Cv.y, acc[k0i+2].x);
            acc[k0i+2].y = fmaf(a.y, Cv.z, acc[k0i+2].y);
            acc[k0i+2].z = fmaf(a.z, Cv.w, acc[k0i+2].z);
            acc[k0i+2].w = fmaf(a.w, rq,   acc[k0i+2].w);
        }
    }

    float* cp = cv + (size_t)nt * 9 * HW + p;
    const float rcr = 1.0f / CR;
#pragma unroll
    for (int k = 0; k < 9; ++k) {
        float sc = g[k] * BN_INV;
        f32x4 v;
        v.x = relu(fmaf(acc[k].x * rcr, sc, bb[k]));
        v.y = relu(fmaf(acc[k].y * rcr, sc, bb[k]));
        v.z = relu(fmaf(acc[k].z * rcr, sc, bb[k]));
        v.w = relu(fmaf(acc[k].w * rcr, sc, bb[k]));
        *(f32x4*)(cp + (size_t)k * HW) = v;
    }
}

// k3: out[nt,o,p] = relu( bn23( sum_k w2[o,k]*cv[nt,k,p] ) + x[nt,o,p] )
// float4: thread = 4 pixels. 64-thr blocks, grid 784.
__global__ __launch_bounds__(64) void k3_conv22(const float* __restrict__ cv,
                                                const float* __restrict__ w2,
                                                const float* __restrict__ g,
                                                const float* __restrict__ bb,
                                                const float* __restrict__ x,
                                                float* __restrict__ out) {
    int gt = blockIdx.x * 64 + threadIdx.x;    // 0..50175
    int nt = gt / 784;
    int pm = (gt - nt * 784) * 4;

    const float* cp = cv + (size_t)nt * 9 * HW + pm;
    f32x4 cvv[9];
#pragma unroll
    for (int k = 0; k < 9; ++k) cvv[k] = *(const f32x4*)(cp + (size_t)k * HW);

    const float* xp = x   + (size_t)nt * (C * HW) + pm;
    float*       op = out + (size_t)nt * (C * HW) + pm;

#pragma unroll 8
    for (int o = 0; o < C; ++o) {
        f32x4 xr = *(const f32x4*)(xp + (size_t)o * HW);
        float sc = g[o] * BN_INV, bv = bb[o];
        f32x4 s = (f32x4)0.0f;
#pragma unroll
        for (int k = 0; k < 9; ++k) {
            float wv = w2[o * 9 + k];
            s.x = fmaf(wv, cvv[k].x, s.x);
            s.y = fmaf(wv, cvv[k].y, s.y);
            s.z = fmaf(wv, cvv[k].z, s.z);
            s.w = fmaf(wv, cvv[k].w, s.w);
        }
        f32x4 v;
        v.x = relu(fmaf(s.x, sc, bv) + xr.x);
        v.y = relu(fmaf(s.y, sc, bv) + xr.y);
        v.z = relu(fmaf(s.z, sc, bv) + xr.z);
        v.w = relu(fmaf(s.w, sc, bv) + xr.w);
        *(f32x4*)(op + (size_t)o * HW) = v;
    }
}

extern "C" void kernel_launch(void* const* d_in, const int* in_sizes, int n_in,
                              void* d_out, int out_size, void* d_ws, size_t ws_size,
                              hipStream_t stream) {
    const float* x   = (const float*)d_in[0];
    const float* w21 = (const float*)d_in[1];
    const float* g21 = (const float*)d_in[2];
    const float* b21 = (const float*)d_in[3];
    const float* g22 = (const float*)d_in[4];
    const float* b22 = (const float*)d_in[5];
    const float* w22 = (const float*)d_in[6];
    const float* g23 = (const float*)d_in[7];
    const float* b23 = (const float*)d_in[8];
    float* out = (float*)d_out;

    // y (64*64*3136 fp32 = 51.4MB) lives in d_out (dead before k3 overwrites it)
    float* yb  = out;
    // cv (7.2MB) + wbf (32KB) live in d_ws
    float* cvb = (float*)d_ws;
    unsigned short* wbf = (unsigned short*)(cvb + (size_t)NT * 9 * HW);

    k0_cvt_w <<<64,  256, 0, stream>>>(w21, wbf);
    k1_mfma  <<<784, 256, 0, stream>>>(x, wbf, g21, b21, yb);
    k2_corr  <<<784, 64,  0, stream>>>(yb, g22, b22, cvb);
    k3_conv22<<<784, 64,  0, stream>>>(cvb, w22, g23, b23, x, out);
}

// Round 5
// 175.591 us; speedup vs baseline: 1.2622x; 1.2622x over previous
//
#include <hip/hip_runtime.h>
#include <hip/hip_bf16.h>

#define HW     3136      // 56*56
#define WIDTH  56
#define C      256
#define CR     64
#define NT     64
#define TT     8
#define PW     64        // padded row width (bf16 y)
#define PH     58        // padded rows
#define YPLANE (PH*PW)   // 3712 shorts per (nt,ch) plane

#define BN_INV 0.9999950000374997f   // 1/sqrt(1+1e-5)

typedef __attribute__((ext_vector_type(8))) short short8;
typedef __attribute__((ext_vector_type(8))) unsigned short ushort8;
typedef __attribute__((ext_vector_type(4))) float f32x4;
typedef __attribute__((ext_vector_type(2))) float f32x2;
typedef __attribute__((ext_vector_type(4))) unsigned int uint4v;

static __device__ __forceinline__ float relu(float v) { return fmaxf(v, 0.0f); }
static __device__ __forceinline__ float bf2f(unsigned short u) {
    return __builtin_bit_cast(float, (unsigned)u << 16);
}
static __device__ __forceinline__ unsigned short f2bf(float f) {
    unsigned u = __builtin_bit_cast(unsigned, f);
    unsigned r = (u + 0x7FFFu + ((u >> 16) & 1u)) >> 16;   // RNE
    return (unsigned short)r;
}
static __device__ __forceinline__ unsigned pack2(float a, float b) {
    return (unsigned)f2bf(a) | ((unsigned)f2bf(b) << 16);
}

// k_init: blocks 0..1855 zero the padded y buffer (30.4MB); blocks 1856..1919
// convert conv21_w fp32 -> bf16.
__global__ __launch_bounds__(256) void k_init(const float* __restrict__ w,
                                              unsigned short* __restrict__ wbf,
                                              uint4v* __restrict__ yz) {
    int blk = blockIdx.x, tid = threadIdx.x;
    if (blk < 1856) {
        size_t b = (size_t)blk * 1024 + tid;
        uint4v z = (uint4v)0u;
        yz[b] = z; yz[b + 256] = z; yz[b + 512] = z; yz[b + 768] = z;
    } else {
        int i = (blk - 1856) * 256 + tid;
        wbf[i] = f2bf(w[i]);
    }
}

// k1: y[nt,o,(r,c)] = relu(bn21( sum_c w[o,c]*x[nt,c,p] )) -> bf16 padded layout.
// Barrier-free MFMA K-loop; wave owns frame nt = 4*(blk/49)+wv, 64-pixel strip.
__global__ __launch_bounds__(256, 2) void k1_mfma(const float* __restrict__ x,
                                                  const unsigned short* __restrict__ wbf,
                                                  const float* __restrict__ g,
                                                  const float* __restrict__ bb,
                                                  unsigned short* __restrict__ y) {
    __shared__ unsigned short Alds[64][264];     // 64 o x (256 c + 8 pad) = 33 KB
    __shared__ unsigned short Blds[4][64][40];   // per-wave 64 px x (32 c + 8 pad) = 20 KB

    const int tid  = threadIdx.x;
    const int lane = tid & 63;
    const int wv   = tid >> 6;
    const int blk  = blockIdx.x;
    const int gq   = blk / 49;
    const int s    = blk - gq * 49;
    const int p0   = s * 64;
    const int nt   = __builtin_amdgcn_readfirstlane(gq * 4 + wv);

    {   // stage A once
        const int o  = tid >> 2;
        const int cb = (tid & 3) * 64;
        const unsigned short* wp = wbf + o * C + cb;
        unsigned short* ap = &Alds[o][cb];
#pragma unroll
        for (int j = 0; j < 8; ++j)
            *(short8*)(ap + j * 8) = *(const short8*)(wp + j * 8);
    }
    __syncthreads();   // the only barrier

    const float* xw = x + (size_t)nt * (C * HW) + p0 + lane;
    unsigned short (*Bw)[40] = Blds[wv];

    f32x4 acc[4][4];
#pragma unroll
    for (int nb = 0; nb < 4; ++nb)
#pragma unroll
        for (int mb = 0; mb < 4; ++mb) acc[nb][mb] = (f32x4)0.0f;

    const int frow = lane & 15;
    const int fk8  = (lane >> 4) * 8;

    float buf[2][32];
#pragma unroll
    for (int j = 0; j < 32; ++j) buf[0][j] = xw[(size_t)j * HW];

#pragma unroll
    for (int ks = 0; ks < 8; ++ks) {
        const int cur = ks & 1;
        if (ks < 7) {
            const float* xn = xw + (size_t)((ks + 1) * 32) * HW;
#pragma unroll
            for (int j = 0; j < 32; ++j) buf[cur ^ 1][j] = xn[(size_t)j * HW];
        }
#pragma unroll
        for (int q = 0; q < 4; ++q) {
            union { unsigned d[4]; short8 v; } pk;
#pragma unroll
            for (int jj = 0; jj < 4; ++jj)
                pk.d[jj] = pack2(buf[cur][q * 8 + 2 * jj], buf[cur][q * 8 + 2 * jj + 1]);
            *(short8*)&Bw[lane][q * 8] = pk.v;
        }
        short8 bfrag[4], afrag[4];
#pragma unroll
        for (int nb = 0; nb < 4; ++nb)
            bfrag[nb] = *(const short8*)&Bw[nb * 16 + frow][fk8];
#pragma unroll
        for (int mb = 0; mb < 4; ++mb)
            afrag[mb] = *(const short8*)&Alds[mb * 16 + frow][ks * 32 + fk8];
#pragma unroll
        for (int nb = 0; nb < 4; ++nb)
#pragma unroll
            for (int mb = 0; mb < 4; ++mb)
                acc[nb][mb] = __builtin_amdgcn_mfma_f32_16x16x32_bf16(
                    afrag[mb], bfrag[nb], acc[nb][mb], 0, 0, 0);
    }

    // epilogue: D col = lane&15 (pixel), row = (lane>>4)*4 + r (output o); bf16 store
    unsigned short* ybase = y + (size_t)nt * CR * YPLANE;
    const int rbase = (lane >> 4) * 4;
#pragma unroll
    for (int nb = 0; nb < 4; ++nb) {
        const int p = p0 + nb * 16 + frow;
        const int r = p / WIDTH;
        const int c = p - r * WIDTH;
        const int pidx = (r + 1) * PW + (c + 1);
#pragma unroll
        for (int mb = 0; mb < 4; ++mb)
#pragma unroll
            for (int rr = 0; rr < 4; ++rr) {
                int o = mb * 16 + rbase + rr;
                float v = relu(fmaf(acc[nb][mb][rr], g[o] * BN_INV, bb[o]));
                ybase[(size_t)o * YPLANE + pidx] = f2bf(v);
            }
    }
}

// k2: cv[nt,k,p] = relu(bn22( (1/CR) * sum_ch y1*y2(shifted) )).
// Thread = (task, ch-quarter); task = (nt, row, 8-col group). No masks (halo).
__global__ __launch_bounds__(256) void k2_corr(const unsigned short* __restrict__ y,
                                               const float* __restrict__ g,
                                               const float* __restrict__ bb,
                                               float* __restrict__ cv) {
    int gt   = blockIdx.x * 256 + threadIdx.x;   // 0..100351
    int h    = gt & 3;                           // ch quarter
    int task = gt >> 2;                          // 0..25087
    int nt   = task / 392;                       // 392 = 56 rows * 7 cgroups
    int rm   = task - nt * 392;
    int r    = rm / 7;
    int cg   = rm - r * 7;
    int c0   = cg * 8;
    int nt2  = ((nt & (TT - 1)) < TT - 1) ? nt + 1 : nt;

    const unsigned short* y1 = y + ((size_t)nt * CR + h * 16) * YPLANE
                                 + (size_t)(r + 1) * PW + c0;
    const unsigned short* y2 = y + ((size_t)nt2 * CR + h * 16) * YPLANE
                                 + (size_t)r * PW + c0;

    float acc[9][8];
#pragma unroll
    for (int k = 0; k < 9; ++k)
#pragma unroll
        for (int px = 0; px < 8; ++px) acc[k][px] = 0.0f;

#pragma unroll 2
    for (int ch = 0; ch < 16; ++ch) {
        const unsigned short* p1 = y1 + (size_t)ch * YPLANE;
        ushort8 a8 = *(const ushort8*)p1;
        unsigned at = *(const unsigned*)(p1 + 8);
        float a[8];
#pragma unroll
        for (int j = 0; j < 7; ++j) a[j] = bf2f(a8[j + 1]);
        a[7] = bf2f((unsigned short)(at & 0xffffu));

        const unsigned short* p2 = y2 + (size_t)ch * YPLANE;
#pragma unroll
        for (int dy = 0; dy < 3; ++dy) {
            const unsigned short* pr = p2 + dy * PW;
            ushort8 b8 = *(const ushort8*)pr;
            unsigned bt = *(const unsigned*)(pr + 8);
            float w[10];
#pragma unroll
            for (int j = 0; j < 8; ++j) w[j] = bf2f(b8[j]);
            w[8] = bf2f((unsigned short)(bt & 0xffffu));
            w[9] = bf2f((unsigned short)(bt >> 16));
#pragma unroll
            for (int dx = 0; dx < 3; ++dx) {
                int k = dy * 3 + dx;
#pragma unroll
                for (int px = 0; px < 8; ++px)
                    acc[k][px] = fmaf(a[px], w[px + dx], acc[k][px]);
            }
        }
    }

    // reduce across the 4 ch-quarter lanes (xor 1, xor 2)
#pragma unroll
    for (int k = 0; k < 9; ++k)
#pragma unroll
        for (int px = 0; px < 8; ++px) {
            float v = acc[k][px];
            v += __shfl_xor(v, 1);
            v += __shfl_xor(v, 2);
            acc[k][px] = v;
        }

    if (h == 0) {
        float* cp = cv + (size_t)nt * 9 * HW + r * WIDTH + c0;
        const float rcr = 1.0f / CR;
#pragma unroll
        for (int k = 0; k < 9; ++k) {
            float sc = g[k] * BN_INV, bv = bb[k];
            f32x4 lo, hi;
            lo.x = relu(fmaf(acc[k][0] * rcr, sc, bv));
            lo.y = relu(fmaf(acc[k][1] * rcr, sc, bv));
            lo.z = relu(fmaf(acc[k][2] * rcr, sc, bv));
            lo.w = relu(fmaf(acc[k][3] * rcr, sc, bv));
            hi.x = relu(fmaf(acc[k][4] * rcr, sc, bv));
            hi.y = relu(fmaf(acc[k][5] * rcr, sc, bv));
            hi.z = relu(fmaf(acc[k][6] * rcr, sc, bv));
            hi.w = relu(fmaf(acc[k][7] * rcr, sc, bv));
            *(f32x4*)(cp + (size_t)k * HW)     = lo;
            *(f32x4*)(cp + (size_t)k * HW + 4) = hi;
        }
    }
}

// k3: out[nt,o,p] = relu( bn23( sum_k w2[o,k]*cv[nt,k,p] ) + x[nt,o,p] ).
// 2 pixels/thread (float2), 392 blocks x 256 thr; o-loop uniform -> s_loads.
__global__ __launch_bounds__(256) void k3_conv22(const float* __restrict__ cv,
                                                 const float* __restrict__ w2,
                                                 const float* __restrict__ g,
                                                 const float* __restrict__ bb,
                                                 const float* __restrict__ x,
                                                 float* __restrict__ out) {
    int gt = blockIdx.x * 256 + threadIdx.x;   // 0..100351
    int nt = gt / 1568;                        // 1568 = 3136/2
    int p2 = (gt - nt * 1568) * 2;

    const float* cp = cv + (size_t)nt * 9 * HW + p2;
    float cvx[9], cvy[9];
#pragma unroll
    for (int k = 0; k < 9; ++k) {
        f32x2 v = *(const f32x2*)(cp + (size_t)k * HW);
        cvx[k] = v.x; cvy[k] = v.y;
    }

    const float* xp = x   + (size_t)nt * (C * HW) + p2;
    float*       op = out + (size_t)nt * (C * HW) + p2;

#pragma unroll 8
    for (int o = 0; o < C; ++o) {
        const float* wr = w2 + o * 9;
        f32x2 xr = *(const f32x2*)(xp + (size_t)o * HW);
        float sx = 0.0f, sy = 0.0f;
#pragma unroll
        for (int k = 0; k < 9; ++k) {
            float wv = wr[k];
            sx = fmaf(wv, cvx[k], sx);
            sy = fmaf(wv, cvy[k], sy);
        }
        float sc = g[o] * BN_INV, bv = bb[o];
        f32x2 rv;
        rv.x = relu(fmaf(sx, sc, bv) + xr.x);
        rv.y = relu(fmaf(sy, sc, bv) + xr.y);
        *(f32x2*)(op + (size_t)o * HW) = rv;
    }
}

extern "C" void kernel_launch(void* const* d_in, const int* in_sizes, int n_in,
                              void* d_out, int out_size, void* d_ws, size_t ws_size,
                              hipStream_t stream) {
    const float* x   = (const float*)d_in[0];
    const float* w21 = (const float*)d_in[1];
    const float* g21 = (const float*)d_in[2];
    const float* b21 = (const float*)d_in[3];
    const float* g22 = (const float*)d_in[4];
    const float* b22 = (const float*)d_in[5];
    const float* w22 = (const float*)d_in[6];
    const float* g23 = (const float*)d_in[7];
    const float* b23 = (const float*)d_in[8];
    float* out = (float*)d_out;

    // y: bf16 padded [64][64][58][64] = 30.4MB, lives in d_out (dead before k3)
    unsigned short* yb = (unsigned short*)d_out;
    // cv (7.2MB fp32) + wbf (32KB) live in d_ws
    float* cvb = (float*)d_ws;
    unsigned short* wbf = (unsigned short*)(cvb + (size_t)NT * 9 * HW);

    k_init   <<<1920, 256, 0, stream>>>(w21, wbf, (uint4v*)yb);
    k1_mfma  <<<784,  256, 0, stream>>>(x, wbf, g21, b21, yb);
    k2_corr  <<<392,  256, 0, stream>>>(yb, g22, b22, cvb);
    k3_conv22<<<392,  256, 0, stream>>>(cvb, w22, g23, b23, x, out);
}